// Round 3
// baseline (179.764 us; speedup 1.0000x reference)
//
#include <hip/hip_runtime.h>
#include <hip/hip_bf16.h>
#include <stdint.h>

typedef __bf16 bf16x8 __attribute__((ext_vector_type(8)));
typedef float f32x4 __attribute__((ext_vector_type(4)));

#define GLB_AS __attribute__((address_space(1)))
#define LDS_AS __attribute__((address_space(3)))

__device__ __forceinline__ void gload_lds16(const void* g, void* l) {
    // dest is wave-uniform base; HW writes base + lane*16
    __builtin_amdgcn_global_load_lds((GLB_AS void*)(g), (LDS_AS void*)(l), 16, 0, 0);
}

#define GM 8192
#define GN 8192
#define GK 1024
#define NT (GK / 64)   // 16 K-tiles of 64
#define NI (NT / 2)    // 8 iterations, 2 K-tiles each

// ---------------------------------------------------------------------------
// Kernel 1: row L2-normalize (x gets +1e-7 first), write bf16.
// ---------------------------------------------------------------------------
__global__ __launch_bounds__(256) void normalize_rows(
    const float* __restrict__ x, const float* __restrict__ ref,
    __bf16* __restrict__ outA, __bf16* __restrict__ outB)
{
    const int row = blockIdx.x;
    const bool isX = row < 8192;
    const size_t r = isX ? (size_t)row : (size_t)(row - 8192);
    const float* src = isX ? (x + r * 1024) : (ref + r * 1024);
    __bf16* dst = isX ? (outA + r * 1024) : (outB + r * 1024);
    const float eps = isX ? 1e-7f : 0.0f;

    const int t = threadIdx.x;
    float4 v = reinterpret_cast<const float4*>(src)[t];
    v.x += eps; v.y += eps; v.z += eps; v.w += eps;
    float ss = v.x * v.x + v.y * v.y + v.z * v.z + v.w * v.w;

    #pragma unroll
    for (int o = 32; o; o >>= 1) ss += __shfl_xor(ss, o, 64);

    __shared__ float red[4];
    const int wv = t >> 6, lane = t & 63;
    if (lane == 0) red[wv] = ss;
    __syncthreads();
    const float tot = red[0] + red[1] + red[2] + red[3];
    const float inv = rsqrtf(fmaxf(tot, 1e-12f));

    __bf16 b[4];
    b[0] = (__bf16)(v.x * inv);
    b[1] = (__bf16)(v.y * inv);
    b[2] = (__bf16)(v.z * inv);
    b[3] = (__bf16)(v.w * inv);
    uint2 pk;
    __builtin_memcpy(&pk, b, 8);
    reinterpret_cast<uint2*>(dst)[t] = pk;
}

// ---------------------------------------------------------------------------
// Kernel 2: 256x256 8-phase bf16 GEMM (C = A . B^T), plain-HIP HK-style.
//  - 512 thr = 8 waves (2M x 4N), per-wave 128x64 output, acc[8][4] f32x4
//  - swapped-operand MFMA: mfma(B,A) -> lane holds 4 consecutive C-cols
//    (row = base + lane&15, cols = base + (lane>>4)*4 + j) -> dwordx4 stores
//  - stores issued at quadrant finalization (ph5-8 of the last iteration),
//    fire-and-forget (no trailing waits) so they drain under the next
//    generation's compute
//  - generation-aware tile map: dispatch-order generation = 16x16 tile
//    square; each XCD gets a 4x8 rect (L2-resident staging panels)
// ---------------------------------------------------------------------------
__global__ __launch_bounds__(512, 2) void gemm_bt8(
    const __bf16* __restrict__ A, const __bf16* __restrict__ B,
    float* __restrict__ C)
{
    __shared__ __bf16 As[2][2][128][64];   // 64 KB
    __shared__ __bf16 Bs[2][2][128][64];   // 64 KB

    // generation-aware, XCD-clustered tile map (1024 tiles = 32x32 grid)
    const int bid = blockIdx.x;
    const int g  = bid >> 8;          // generation 0..3 (dispatch order)
    const int x  = bid & 7;           // XCD
    const int ii = (bid >> 3) & 31;   // index within gen x XCD
    const int tm = (g & 1) * 16 + (x & 3) * 4 + (ii & 3);
    const int tn = (g >> 1) * 16 + (x >> 2) * 8 + (ii >> 2);
    const size_t rowM0 = (size_t)tm * 256;
    const size_t rowN0 = (size_t)tn * 256;

    const int tid  = threadIdx.x;
    const int wave = tid >> 6;
    const int lane = tid & 63;
    const int wr = wave >> 2;      // 0..1
    const int wc = wave & 3;       // 0..3

    const int srow  = lane >> 3;            // staging: row within 8-row chunk
    const int sslot = (lane & 7) ^ srow;    // inverse-swizzled global k-slot
    const int fr = lane & 15;               // frag row
    const int fs = lane >> 4;               // frag k-subslot

    bf16x8 af[4][2];       // A frags: current qm, [m_local][ks]
    bf16x8 bq[2][2][2];    // B frags: both qn held, [qn][n_local][ks]
    f32x4  acc[8][4] = {};

// stage one A half-tile (128 LDS rows x 128 B): global row = j*128 + h*64 + r
#define STAGE_A(T, h, b) { \
    _Pragma("unroll") \
    for (int j = 0; j < 2; ++j) { \
        const size_t grow = rowM0 + (size_t)(j) * 128 + (h) * 64 + wave * 8 + srow; \
        const char* src = (const char*)A + (grow * GK + (size_t)(T) * 64) * 2 + sslot * 16; \
        char* dst = (char*)&As[b][h][0][0] + (j * 64 + wave * 8) * 128; \
        gload_lds16(src, dst); } }

// stage one B half-tile: LDS row l -> global B-row = (l>>5)*64 + h*32 + (l&31)
#define STAGE_B(T, h, b) { \
    _Pragma("unroll") \
    for (int j = 0; j < 2; ++j) { \
        const int l = j * 64 + wave * 8 + srow; \
        const size_t grow = rowN0 + (size_t)(l >> 5) * 64 + (h) * 32 + (l & 31); \
        const char* src = (const char*)B + (grow * GK + (size_t)(T) * 64) * 2 + sslot * 16; \
        char* dst = (char*)&Bs[b][h][0][0] + (j * 64 + wave * 8) * 128; \
        gload_lds16(src, dst); } }

#define LDA(qm, b) { \
    _Pragma("unroll") \
    for (int m = 0; m < 4; ++m) { \
        const int l = wr * 64 + m * 16 + fr; \
        _Pragma("unroll") \
        for (int ks = 0; ks < 2; ++ks) { \
            const int slot = (ks * 4 + fs) ^ (l & 7); \
            af[m][ks] = *(const bf16x8*)((const char*)&As[b][qm][0][0] + l * 128 + slot * 16); } } }

#define LDB(qn, b) { \
    _Pragma("unroll") \
    for (int n = 0; n < 2; ++n) { \
        const int l = wc * 32 + n * 16 + fr; \
        _Pragma("unroll") \
        for (int ks = 0; ks < 2; ++ks) { \
            const int slot = (ks * 4 + fs) ^ (l & 7); \
            bq[qn][n][ks] = *(const bf16x8*)((const char*)&Bs[b][qn][0][0] + l * 128 + slot * 16); } } }

// swapped operands: D = mfma(B_frag, A_frag) -> lane holds one C-row's
// 4 consecutive cols per reg quad
#define QMFMA(qm, qn) { \
    __builtin_amdgcn_s_setprio(1); \
    _Pragma("unroll") \
    for (int ks = 0; ks < 2; ++ks) \
    _Pragma("unroll") \
    for (int m = 0; m < 4; ++m) \
    _Pragma("unroll") \
    for (int n = 0; n < 2; ++n) \
        acc[(qm) * 4 + m][(qn) * 2 + n] = __builtin_amdgcn_mfma_f32_16x16x32_bf16( \
            bq[qn][n][ks], af[m][ks], acc[(qm) * 4 + m][(qn) * 2 + n], 0, 0, 0); \
    __builtin_amdgcn_s_setprio(0); }

// store one finalized quadrant: 8 x dwordx4, fire-and-forget
#define STORE_QUAD(qm, qn) { \
    _Pragma("unroll") \
    for (int m = 0; m < 4; ++m) \
    _Pragma("unroll") \
    for (int n = 0; n < 2; ++n) { \
        const size_t row = rowM0 + (size_t)wr * 128 + (qm) * 64 + m * 16 + (lane & 15); \
        const size_t col = rowN0 + (size_t)wc * 64 + (qn) * 32 + n * 16 + (lane >> 4) * 4; \
        *reinterpret_cast<f32x4*>(&C[row * (size_t)GN + col]) = acc[(qm) * 4 + m][(qn) * 2 + n]; } }

#define BAR() __builtin_amdgcn_s_barrier()
#define WAIT_LGKM0() { asm volatile("s_waitcnt lgkmcnt(0)" ::: "memory"); __builtin_amdgcn_sched_barrier(0); }
#define WAIT_VM(n)   { asm volatile("s_waitcnt vmcnt(" #n ")" ::: "memory"); __builtin_amdgcn_sched_barrier(0); }

    // prologue: tile0 fully, tile1 minus A-h1 (staged at phase 1)
    STAGE_A(0, 0, 0); STAGE_A(0, 1, 0); STAGE_B(0, 0, 0); STAGE_B(0, 1, 0);
    STAGE_A(1, 0, 1); STAGE_B(1, 0, 1); STAGE_B(1, 1, 1);
    WAIT_VM(6);
    BAR();

    #pragma unroll 1
    for (int i = 0; i < NI; ++i) {
        const int t1 = 2 * i + 1, t2 = 2 * i + 2, t3 = 2 * i + 3;
        const bool more = (i < NI - 1);

        // phase 1: Q(0,0) of tile t0 (buf0); stage t1 A-h1
        LDA(0, 0); LDB(0, 0);
        STAGE_A(t1, 1, 1);
        BAR(); WAIT_LGKM0();
        QMFMA(0, 0);
        BAR();
        // phase 2: Q(0,1); stage t2 A-h0 (A-h0 of t0 free after ph1)
        LDB(1, 0);
        if (more) STAGE_A(t2, 0, 0);
        BAR(); WAIT_LGKM0();
        QMFMA(0, 1);
        BAR();
        // phase 3: Q(1,0); stage t2 B-h0 (B-h0 of t0 read only at ph1)
        LDA(1, 0);
        if (more) STAGE_B(t2, 0, 0);
        BAR(); WAIT_LGKM0();
        QMFMA(1, 0);
        BAR();
        // phase 4: Q(1,1); stage t2 B-h1; counted vmcnt covers tile t1
        if (more) { STAGE_B(t2, 1, 0); WAIT_VM(6); }
        else      { WAIT_VM(0); }   // drain loads; no stores issued yet
        BAR();
        QMFMA(1, 1);
        BAR();
        // phase 5: Q(0,0) of tile t1 (buf1); stage t2 A-h1 (free after ph3)
        LDA(0, 1); LDB(0, 1);
        if (more) STAGE_A(t2, 1, 0);
        BAR(); WAIT_LGKM0();
        QMFMA(0, 0);
        if (!more) STORE_QUAD(0, 0);
        BAR();
        // phase 6: Q(0,1); stage t3 A-h0 (A-h0 of t1 free after ph5)
        LDB(1, 1);
        if (more) STAGE_A(t3, 0, 1);
        BAR(); WAIT_LGKM0();
        QMFMA(0, 1);
        if (!more) STORE_QUAD(0, 1);
        BAR();
        // phase 7: Q(1,0); stage t3 B-h0
        LDA(1, 1);
        if (more) STAGE_B(t3, 0, 1);
        BAR(); WAIT_LGKM0();
        QMFMA(1, 0);
        if (!more) STORE_QUAD(1, 0);
        BAR();
        // phase 8: Q(1,1); stage t3 B-h1; counted vmcnt covers tile t2
        if (more) {
            STAGE_B(t3, 1, 1); WAIT_VM(6);
            BAR();
            QMFMA(1, 1);
            BAR();
        } else {
            // no wait: nothing left to protect; let stores drain async
            BAR();
            QMFMA(1, 1);
            STORE_QUAD(1, 1);
        }
    }

#undef STAGE_A
#undef STAGE_B
#undef LDA
#undef LDB
#undef QMFMA
#undef STORE_QUAD
#undef BAR
#undef WAIT_LGKM0
#undef WAIT_VM
}

// ---------------------------------------------------------------------------
// Fallback (only if d_ws is too small): naive fp32, correct but slow.
// ---------------------------------------------------------------------------
__global__ __launch_bounds__(256) void naive_pairwise(
    const float* __restrict__ x, const float* __restrict__ ref,
    float* __restrict__ out)
{
    const int row = blockIdx.x >> 5;
    const int j = (blockIdx.x & 31) * 256 + threadIdx.x;
    const float* xr = x + (size_t)row * 1024;
    const float* rr = ref + (size_t)j * 1024;

    __shared__ float xs[1024];
    float part = 0.f;
    for (int k = threadIdx.x; k < 1024; k += 256) {
        float v = xr[k] + 1e-7f;
        xs[k] = v;
        part += v * v;
    }
    #pragma unroll
    for (int o = 32; o; o >>= 1) part += __shfl_xor(part, o, 64);
    __shared__ float red[4];
    if ((threadIdx.x & 63) == 0) red[threadIdx.x >> 6] = part;
    __syncthreads();
    const float ssx = red[0] + red[1] + red[2] + red[3];

    float ssr = 0.f, dot = 0.f;
    for (int k = 0; k < 1024; ++k) {
        float r = rr[k];
        ssr += r * r;
        dot += r * xs[k];
    }
    out[(size_t)row * 8192 + j] =
        dot * rsqrtf(fmaxf(ssx, 1e-12f)) * rsqrtf(fmaxf(ssr, 1e-12f));
}

extern "C" void kernel_launch(void* const* d_in, const int* in_sizes, int n_in,
                              void* d_out, int out_size, void* d_ws, size_t ws_size,
                              hipStream_t stream) {
    const float* x   = (const float*)d_in[0];   // [4,2048,1024] -> [8192][1024]
    const float* ref = (const float*)d_in[1];   // [8192][1024]
    float* out = (float*)d_out;                 // [8192][8192]

    const size_t need = (size_t)GM * GK * sizeof(__bf16) * 2;  // 32 MB
    if (ws_size >= need) {
        __bf16* wsA = (__bf16*)d_ws;
        __bf16* wsB = wsA + (size_t)GM * GK;
        normalize_rows<<<16384, 256, 0, stream>>>(x, ref, wsA, wsB);
        gemm_bt8<<<(GM / 256) * (GN / 256), 512, 0, stream>>>(wsA, wsB, out);
    } else {
        naive_pairwise<<<8192 * 32, 256, 0, stream>>>(x, ref, out);
    }
}